// Round 6
// baseline (781.868 us; speedup 1.0000x reference)
//
#include <hip/hip_runtime.h>

#define NN 2048
#define BB 8
#define KT 416            // 5 slots * 80 rows + 16 zero pad rows
#define SLOT (80 * NN)

typedef __bf16 bf16;
typedef __bf16 bf16x4 __attribute__((ext_vector_type(4)));
typedef __bf16 bf16x8 __attribute__((ext_vector_type(8)));
typedef float  f32x4  __attribute__((ext_vector_type(4)));

// Barrier that waits ONLY on LDS ops (lgkmcnt) — used by proj kernels.
__device__ __forceinline__ void bar_lgkm() {
    asm volatile("s_waitcnt lgkmcnt(0)" ::: "memory");
    __builtin_amdgcn_s_barrier();
}

// ---------------------------------------------------------------------------
// K0: fold Chebyshev (T2 = 2A^2x - x) + duplicated-X blocks into transposed
// bf16 weights Wg'[96][416], Wu'[32][416]; k = t*80 + c, pad cols zeroed.
// ---------------------------------------------------------------------------
__global__ void prep_weights(const float* __restrict__ gw, const float* __restrict__ uw,
                             bf16* __restrict__ Wg, bf16* __restrict__ Wu)
{
    int i = blockIdx.x * 256 + threadIdx.x;
    if (i < 96 * KT) {
        int o = i / KT, k = i % KT, t = k / 80, c = k % 80;
        float v = 0.0f;
        if (c < 66) {
            if (t == 0)      v = gw[c*96+o] - gw[(132+c)*96+o] + gw[(198+c)*96+o] - gw[(330+c)*96+o];
            else if (t == 1) v = gw[(66+c)*96+o];
            else if (t == 2) v = 2.0f * gw[(132+c)*96+o];
            else if (t == 3) v = gw[(264+c)*96+o];
            else             v = 2.0f * gw[(330+c)*96+o];
        }
        Wg[i] = (bf16)v;
    }
    if (i < 32 * KT) {
        int o = i / KT, k = i % KT, t = k / 80, c = k % 80;
        float v = 0.0f;
        if (c < 66) {
            if (t == 0)      v = uw[c*32+o] - uw[(132+c)*32+o] + uw[(198+c)*32+o] - uw[(330+c)*32+o];
            else if (t == 1) v = uw[(66+c)*32+o];
            else if (t == 2) v = 2.0f * uw[(132+c)*32+o];
            else if (t == 3) v = uw[(264+c)*32+o];
            else             v = 2.0f * uw[(330+c)*32+o];
        }
        Wu[i] = (bf16)v;
    }
}

// ---------------------------------------------------------------------------
// K0b: streaming f32 -> bf16 convert of all 16 support matrices (268->134 MB).
// One pass at HBM speed; downstream gemm hops read the L3-resident bf16 copy.
// ---------------------------------------------------------------------------
__global__ __launch_bounds__(256)
void a2bf(const float* __restrict__ s, bf16* __restrict__ d)
{
    const float4* s4 = (const float4*)s;
    uint4* d4 = (uint4*)d;
    const size_t n8 = (size_t)16 * NN * NN / 8;
    for (size_t i = (size_t)blockIdx.x * 256 + threadIdx.x; i < n8;
         i += (size_t)gridDim.x * 256) {
        float4 u = s4[2 * i], v = s4[2 * i + 1];
        bf16x8 r;
        r[0]=(bf16)u.x; r[1]=(bf16)u.y; r[2]=(bf16)u.z; r[3]=(bf16)u.w;
        r[4]=(bf16)v.x; r[5]=(bf16)v.y; r[6]=(bf16)v.z; r[7]=(bf16)v.w;
        d4[i] = *(uint4*)&r;
    }
}

// ---------------------------------------------------------------------------
// K1: 64-node tiles. mr = sigmoid(gate_in@mlp_w+b), state = mr*s1+(1-mr)*s2,
// build T slot0 = X^T basis (rows 0..79, pads zero) with coalesced 128B row
// writes via LDS transpose. Also zeroes T pad rows 400..415.
// ---------------------------------------------------------------------------
__global__ __launch_bounds__(256)
void prep_nodes(const float* __restrict__ xt, const float* __restrict__ s1,
                const float* __restrict__ s2, const float* __restrict__ ge,
                const float* __restrict__ mlp_w, const float* __restrict__ mlp_b,
                float* __restrict__ state, bf16* __restrict__ T)
{
    __shared__ float wl[74 * 32];
    __shared__ float bl[32];
    __shared__ __align__(16) float statel[64][36];
    __shared__ __align__(16) bf16  Xl[80][72];
    const int tid = threadIdx.x;

    for (int i = tid; i < 592; i += 256) ((float4*)wl)[i] = ((const float4*)mlp_w)[i];
    if (tid < 32) bl[tid] = mlp_b[tid];
    {   // zero T pad rows (rows 400..415 per batch): this block's 2KB chunk
        int bb = blockIdx.x >> 5, chunk = blockIdx.x & 31;
        uint2* dst = (uint2*)((char*)T + ((size_t)bb * KT * NN + 400 * NN) * 2 + (size_t)chunk * 2048);
        dst[tid] = make_uint2(0u, 0u);
    }
    for (int i = tid; i < 14 * 64; i += 256) Xl[66 + (i >> 6)][i & 63] = (bf16)0.0f;
    __syncthreads();

    const int nl = tid & 63, og = tid >> 6, o0 = og * 8;
    const size_t node0 = (size_t)blockIdx.x * 64;
    const size_t node = node0 + nl;
    const int b = (int)(node0 >> 11);
    const int nb0 = (int)(node0 & 2047);
    const float* p1 = s1 + node * 32;
    const float* p2 = s2 + node * 32;
    const float* pg = ge + node * 8;

    float acc[8];
    #pragma unroll
    for (int j = 0; j < 8; ++j) acc[j] = bl[o0 + j];
    float2 px = *(const float2*)(xt + node * 2);
    #pragma unroll
    for (int j = 0; j < 8; ++j) acc[j] += px.x * wl[o0 + j] + px.y * wl[32 + o0 + j];

    float k1[8], k2[8];
    #pragma unroll
    for (int ii = 0; ii < 8; ++ii) {
        float4 v = *(const float4*)(p1 + ii * 4);
        const float* vp = (const float*)&v;
        if (ii == 2 * og)     { k1[0]=vp[0]; k1[1]=vp[1]; k1[2]=vp[2]; k1[3]=vp[3]; }
        if (ii == 2 * og + 1) { k1[4]=vp[0]; k1[5]=vp[1]; k1[6]=vp[2]; k1[7]=vp[3]; }
        #pragma unroll
        for (int p = 0; p < 4; ++p) {
            #pragma unroll
            for (int j = 0; j < 8; ++j) acc[j] += vp[p] * wl[(2 + ii*4 + p) * 32 + o0 + j];
        }
    }
    #pragma unroll
    for (int ii = 0; ii < 8; ++ii) {
        float4 v = *(const float4*)(p2 + ii * 4);
        const float* vp = (const float*)&v;
        if (ii == 2 * og)     { k2[0]=vp[0]; k2[1]=vp[1]; k2[2]=vp[2]; k2[3]=vp[3]; }
        if (ii == 2 * og + 1) { k2[4]=vp[0]; k2[5]=vp[1]; k2[6]=vp[2]; k2[7]=vp[3]; }
        #pragma unroll
        for (int p = 0; p < 4; ++p) {
            #pragma unroll
            for (int j = 0; j < 8; ++j) acc[j] += vp[p] * wl[(34 + ii*4 + p) * 32 + o0 + j];
        }
    }
    #pragma unroll
    for (int ii = 0; ii < 2; ++ii) {
        float4 v = *(const float4*)(pg + ii * 4);
        const float* vp = (const float*)&v;
        #pragma unroll
        for (int p = 0; p < 4; ++p) {
            #pragma unroll
            for (int j = 0; j < 8; ++j) acc[j] += vp[p] * wl[(66 + ii*4 + p) * 32 + o0 + j];
        }
    }
    #pragma unroll
    for (int j = 0; j < 8; ++j) {
        float mr = 1.0f / (1.0f + __expf(-acc[j]));
        statel[nl][o0 + j] = mr * k1[j] + (1.0f - mr) * k2[j];
        Xl[2 + o0 + j][nl]  = (bf16)k1[j];
        Xl[34 + o0 + j][nl] = (bf16)k2[j];
    }
    if (og == 0) { Xl[0][nl] = (bf16)px.x; Xl[1][nl] = (bf16)px.y; }
    __syncthreads();

    for (int i = tid; i < 512; i += 256) {
        int n_ = i >> 3, c = (i & 7) * 4;
        *(float4*)&state[node0 * 32 + n_ * 32 + c] = *(const float4*)&statel[n_][c];
    }
    bf16* Tb = T + (size_t)b * KT * NN;
    for (int i = tid; i < 640; i += 256) {
        int r = i >> 3, seg = i & 7;
        *(uint4*)(Tb + (size_t)r * NN + nb0 + seg * 8) = *(const uint4*)&Xl[r][seg * 8];
    }
}

// ---------------------------------------------------------------------------
// K2: C^T(80x2048 bf16) = A(2048x2048) @ T-slot, ZERO LDS / ZERO BARRIERS.
// Each wave is a fully independent stream: A-fragments (bf16, L3-resident
// Abf) and B-fragments (L2-resident T-slot, rows ct*16+frow with 64B/row
// coalescing) load global->register->MFMA. Depth-2 register prefetch, BK=64.
// Rationale: round-5 counters (MfmaUtil 2.8%, VALU 1.4%, HBM 16%, all idle)
// showed the barrier-lockstep LDS pipeline was latency-serialized; the fix is
// more independent streams, not better waits. F32=1 is the no-workspace
// fallback reading f32 supports directly.
// ---------------------------------------------------------------------------
template<int F32>
__global__ __launch_bounds__(256, 2)
void gemm_direct(const float* __restrict__ Aall, const bf16* __restrict__ Abf,
                 bf16* __restrict__ T, int in0, int in1, int out0, int out1)
{
    const int sb = blockIdx.y;
    const int s = sb >> 3, b = sb & 7;
    const int m0 = blockIdx.x * 64;
    const int tid = threadIdx.x, wave = tid >> 6, lane = tid & 63;
    const int frow = lane & 15, fko = (lane >> 4) * 8;
    const int am = m0 + wave * 16 + frow;             // this lane's A row

    bf16* Tb = T + (size_t)b * KT * NN;
    const bf16* Bt = Tb + (size_t)(s ? in1 : in0) * SLOT;
    bf16*       Ct = Tb + (size_t)(s ? out1 : out0) * SLOT + m0;
    const bf16*  Ap = Abf + (size_t)sb * NN * NN + (size_t)am * NN + fko;
    const float* Af = Aall + (size_t)sb * NN * NN + (size_t)am * NN + fko;
    const bf16*  Bp = Bt + (size_t)frow * NN + fko;   // + ct*16*NN + k0 (+32)

    f32x4 acc[5] = {};

    // two named prefetch sets (depth-2 parity; all indices compile-time)
    uint4 aA0, aA1, aB0, aB1;
    float4 gA[4], gB[4];
    uint4 bbA[5][2], bbB[5][2];

    auto ld = [&](uint4& a0, uint4& a1, float4 (&g)[4], uint4 (&bb)[5][2], int k0) {
        if constexpr (F32) {
            g[0] = *(const float4*)(Af + k0);
            g[1] = *(const float4*)(Af + k0 + 4);
            g[2] = *(const float4*)(Af + k0 + 32);
            g[3] = *(const float4*)(Af + k0 + 36);
        } else {
            a0 = *(const uint4*)(Ap + k0);
            a1 = *(const uint4*)(Ap + k0 + 32);
        }
        #pragma unroll
        for (int ct = 0; ct < 5; ++ct) {
            bb[ct][0] = *(const uint4*)(Bp + (size_t)ct * 16 * NN + k0);
            bb[ct][1] = *(const uint4*)(Bp + (size_t)ct * 16 * NN + k0 + 32);
        }
    };
    auto cv = [&](float4 g0, float4 g1) -> bf16x8 {
        bf16x8 r;
        r[0]=(bf16)g0.x; r[1]=(bf16)g0.y; r[2]=(bf16)g0.z; r[3]=(bf16)g0.w;
        r[4]=(bf16)g1.x; r[5]=(bf16)g1.y; r[6]=(bf16)g1.z; r[7]=(bf16)g1.w;
        return r;
    };
    auto comp = [&](uint4& a0, uint4& a1, float4 (&g)[4], uint4 (&bb)[5][2]) {
        bf16x8 af0, af1;
        if constexpr (F32) { af0 = cv(g[0], g[1]); af1 = cv(g[2], g[3]); }
        else { af0 = *(bf16x8*)&a0; af1 = *(bf16x8*)&a1; }
        #pragma unroll
        for (int ct = 0; ct < 5; ++ct)
            acc[ct] = __builtin_amdgcn_mfma_f32_16x16x32_bf16(af0, *(bf16x8*)&bb[ct][0], acc[ct], 0, 0, 0);
        #pragma unroll
        for (int ct = 0; ct < 5; ++ct)
            acc[ct] = __builtin_amdgcn_mfma_f32_16x16x32_bf16(af1, *(bf16x8*)&bb[ct][1], acc[ct], 0, 0, 0);
    };

    ld(aA0, aA1, gA, bbA, 0);
    ld(aB0, aB1, gB, bbB, 64);
    for (int it = 0; it < 32; it += 2) {
        comp(aA0, aA1, gA, bbA);
        if (it < 30) ld(aA0, aA1, gA, bbA, (it + 2) * 64);
        comp(aB0, aB1, gB, bbB);
        if (it < 29) ld(aB0, aB1, gB, bbB, (it + 3) * 64);
    }

    const int ccol = lane & 15;
    const int crow = (lane >> 4) * 4;
    #pragma unroll
    for (int ct = 0; ct < 5; ++ct) {
        bf16x4 o;
        o[0]=(bf16)acc[ct][0]; o[1]=(bf16)acc[ct][1]; o[2]=(bf16)acc[ct][2]; o[3]=(bf16)acc[ct][3];
        *(bf16x4*)&Ct[(size_t)(ct * 16 + ccol) * NN + wave * 16 + crow] = o;
    }
}

// ---------------------------------------------------------------------------
// K3: gate projection as MFMA GEMM: D[96][2048/b] = Wg'[96][416] @ T[416][2048].
// Weights fully LDS-resident; B-tiles double-buffered with depth-2 register
// prefetch + lgkm-only barriers. Epilogue: sigmoid, write Cand rows 2..65
// (slot0) and rT[b][32][2048].
// ---------------------------------------------------------------------------
__global__ __launch_bounds__(256)
void proj_gate(const bf16* T, const bf16* __restrict__ Wg, const float* __restrict__ gate_b,
               const float* __restrict__ s1, const float* __restrict__ s2,
               bf16* Tmut, float* __restrict__ rT)
{
    __shared__ __align__(16) bf16 Wl[96][424];
    __shared__ __align__(16) bf16 Bl[2][64][44];
    const int b = blockIdx.y, n0 = blockIdx.x * 64, tid = threadIdx.x;
    const bf16* Tb = T + (size_t)b * KT * NN;

    for (int i = tid; i < 96 * 52; i += 256) {
        int r = i / 52, seg = i % 52;
        *(uint4*)&Wl[r][seg * 8] = *(const uint4*)(Wg + (size_t)r * KT + seg * 8);
    }
    const int kk = tid >> 3, seg = tid & 7;
    uint4 rbA, rbB;
    auto gloadv = [&](uint4& r, int k0) { r = *(const uint4*)(Tb + (size_t)(k0 + kk) * NN + n0 + seg * 8); };
    auto scat = [&](int buf, uint4& r) {
        bf16 tmp[8]; *(uint4*)tmp = r;
        #pragma unroll
        for (int j = 0; j < 8; ++j) Bl[buf][seg * 8 + j][kk] = tmp[j];
    };
    const int lane = tid & 63, wave = tid >> 6;
    const int fr = lane & 15, qd = lane >> 4;

    f32x4 acc[6] = {};
    auto comp = [&](int buf, int st) {
        bf16x8 bv = *(const bf16x8*)&Bl[buf][wave * 16 + fr][qd * 8];
        #pragma unroll
        for (int f = 0; f < 6; ++f) {
            bf16x8 av = *(const bf16x8*)&Wl[f * 16 + fr][st * 32 + qd * 8];
            acc[f] = __builtin_amdgcn_mfma_f32_16x16x32_bf16(av, bv, acc[f], 0, 0, 0);
        }
    };

    gloadv(rbA, 0); gloadv(rbB, 32);
    for (int st = 0; st < 12; st += 2) {
        scat(0, rbA);
        gloadv(rbA, (st + 2) * 32);
        bar_lgkm();
        comp(0, st);
        scat(1, rbB);
        if (st < 10) gloadv(rbB, (st + 3) * 32);
        bar_lgkm();
        comp(1, st + 1);
    }
    scat(0, rbA);
    bar_lgkm();
    comp(0, 12);

    const int nn = n0 + wave * 16 + fr;
    const size_t node = (size_t)b * NN + nn;
    bf16* Cd = Tmut + (size_t)b * KT * NN;   // slot 0
    #pragma unroll
    for (int f = 0; f < 6; ++f) {
        const int o0 = f * 16 + qd * 4;
        float4 gb4 = *(const float4*)(gate_b + o0);
        const float* gb = (const float*)&gb4;
        float sg[4];
        #pragma unroll
        for (int r = 0; r < 4; ++r) sg[r] = 1.0f / (1.0f + __expf(-(acc[f][r] + gb[r])));
        if (f < 2) {
            float4 sv4 = *(const float4*)(s1 + node * 32 + o0);
            const float* sv = (const float*)&sv4;
            #pragma unroll
            for (int r = 0; r < 4; ++r) Cd[(size_t)(2 + o0 + r) * NN + nn] = (bf16)(sg[r] * sv[r]);
        } else if (f < 4) {
            const int oo = o0 - 32;
            float4 sv4 = *(const float4*)(s2 + node * 32 + oo);
            const float* sv = (const float*)&sv4;
            #pragma unroll
            for (int r = 0; r < 4; ++r) Cd[(size_t)(34 + oo + r) * NN + nn] = (bf16)(sg[r] * sv[r]);
        } else {
            const int oo = o0 - 64;
            #pragma unroll
            for (int r = 0; r < 4; ++r) rT[((size_t)b * 32 + oo + r) * NN + nn] = sg[r];
        }
    }
}

// ---------------------------------------------------------------------------
// K4: update projection: D[32][2048/b] = Wu'[32][416] @ T[416][2048];
// hc = tanh, h = r*state+(1-r)*hc, transnext = h@hop_w+b. h staged in LDS for
// the 32-dot and coalesced writes. Same depth-2 + lgkm-barrier pipeline.
// ---------------------------------------------------------------------------
__global__ __launch_bounds__(256)
void proj_upd(const bf16* __restrict__ T, const bf16* __restrict__ Wu,
              const float* __restrict__ upd_b, const float* __restrict__ state,
              const float* __restrict__ rT, const float* __restrict__ hop_w,
              const float* __restrict__ hop_b, float* __restrict__ out)
{
    __shared__ __align__(16) bf16 Wl[32][424];
    __shared__ __align__(16) bf16 Bl[2][64][44];
    __shared__ __align__(16) float hsh[64][36];
    __shared__ float hw[1024];
    const int b = blockIdx.y, n0 = blockIdx.x * 64, tid = threadIdx.x;
    const bf16* Tb = T + (size_t)b * KT * NN;

    for (int i = tid; i < 32 * 52; i += 256) {
        int r = i / 52, seg = i % 52;
        *(uint4*)&Wl[r][seg * 8] = *(const uint4*)(Wu + (size_t)r * KT + seg * 8);
    }
    for (int i = tid; i < 256; i += 256) ((float4*)hw)[i] = ((const float4*)hop_w)[i];
    const int kk = tid >> 3, seg = tid & 7;
    uint4 rbA, rbB;
    auto gloadv = [&](uint4& r, int k0) { r = *(const uint4*)(Tb + (size_t)(k0 + kk) * NN + n0 + seg * 8); };
    auto scat = [&](int buf, uint4& r) {
        bf16 tmp[8]; *(uint4*)tmp = r;
        #pragma unroll
        for (int j = 0; j < 8; ++j) Bl[buf][seg * 8 + j][kk] = tmp[j];
    };
    const int lane = tid & 63, wave = tid >> 6;
    const int fr = lane & 15, qd = lane >> 4;

    f32x4 acc[2] = {};
    auto comp = [&](int buf, int st) {
        bf16x8 bv = *(const bf16x8*)&Bl[buf][wave * 16 + fr][qd * 8];
        #pragma unroll
        for (int f = 0; f < 2; ++f) {
            bf16x8 av = *(const bf16x8*)&Wl[f * 16 + fr][st * 32 + qd * 8];
            acc[f] = __builtin_amdgcn_mfma_f32_16x16x32_bf16(av, bv, acc[f], 0, 0, 0);
        }
    };

    gloadv(rbA, 0); gloadv(rbB, 32);
    for (int st = 0; st < 12; st += 2) {
        scat(0, rbA);
        gloadv(rbA, (st + 2) * 32);
        bar_lgkm();
        comp(0, st);
        scat(1, rbB);
        if (st < 10) gloadv(rbB, (st + 3) * 32);
        bar_lgkm();
        comp(1, st + 1);
    }
    scat(0, rbA);
    bar_lgkm();
    comp(0, 12);

    const int nn = n0 + wave * 16 + fr;
    const size_t node = (size_t)b * NN + nn;
    const int nl = wave * 16 + fr;
    #pragma unroll
    for (int f = 0; f < 2; ++f) {
        const int o0 = f * 16 + qd * 4;
        float4 ub4 = *(const float4*)(upd_b + o0);
        const float* ub = (const float*)&ub4;
        float4 st4 = *(const float4*)(state + node * 32 + o0);
        const float* sv = (const float*)&st4;
        #pragma unroll
        for (int r = 0; r < 4; ++r) {
            const int o = o0 + r;
            float hc = tanhf(acc[f][r] + ub[r]);
            float rv = rT[((size_t)b * 32 + o) * NN + nn];
            hsh[nl][o] = rv * sv[r] + (1.0f - rv) * hc;
        }
    }
    __syncthreads();

    const int nl2 = tid & 63, og = tid >> 6;
    const size_t node2 = (size_t)b * NN + n0 + nl2;
    float tac[8];
    #pragma unroll
    for (int j = 0; j < 8; ++j) tac[j] = hop_b[og * 8 + j];
    #pragma unroll
    for (int kc = 0; kc < 8; ++kc) {
        float4 hv4 = *(const float4*)&hsh[nl2][kc * 4];
        const float* hv = (const float*)&hv4;
        #pragma unroll
        for (int p = 0; p < 4; ++p) {
            #pragma unroll
            for (int j = 0; j < 8; ++j) tac[j] += hv[p] * hw[(kc * 4 + p) * 32 + og * 8 + j];
        }
    }
    float* out2 = out + (size_t)BB * NN * 32;
    *(float4*)&out[node2 * 32 + og * 8]     = *(const float4*)&hsh[nl2][og * 8];
    *(float4*)&out[node2 * 32 + og * 8 + 4] = *(const float4*)&hsh[nl2][og * 8 + 4];
    float4 t0; float* t0p = (float*)&t0;
    t0p[0]=tac[0]; t0p[1]=tac[1]; t0p[2]=tac[2]; t0p[3]=tac[3];
    *(float4*)&out2[node2 * 32 + og * 8] = t0;
    t0p[0]=tac[4]; t0p[1]=tac[5]; t0p[2]=tac[6]; t0p[3]=tac[7];
    *(float4*)&out2[node2 * 32 + og * 8 + 4] = t0;
}

// ---------------------------------------------------------------------------
extern "C" void kernel_launch(void* const* d_in, const int* in_sizes, int n_in,
                              void* d_out, int out_size, void* d_ws, size_t ws_size,
                              hipStream_t stream)
{
    const float* xt     = (const float*)d_in[0];
    const float* s1     = (const float*)d_in[1];
    const float* s2     = (const float*)d_in[2];
    const float* ge     = (const float*)d_in[3];
    const float* sup    = (const float*)d_in[4];
    const float* mlp_w  = (const float*)d_in[5];
    const float* mlp_b  = (const float*)d_in[6];
    const float* gate_w = (const float*)d_in[7];
    const float* gate_b = (const float*)d_in[8];
    const float* upd_w  = (const float*)d_in[9];
    const float* upd_b  = (const float*)d_in[10];
    const float* hop_w  = (const float*)d_in[11];
    const float* hop_b  = (const float*)d_in[12];
    float* out = (float*)d_out;

    char* ws = (char*)d_ws;
    size_t off = 0;
    auto alloc = [&](size_t bytes) -> void* {
        void* p = ws + off;
        off += (bytes + 255) & ~(size_t)255;
        return p;
    };
    bf16*  T     = (bf16*) alloc((size_t)BB * KT * NN * 2);
    float* state = (float*)alloc((size_t)BB * NN * 32 * 4);
    float* rT    = (float*)alloc((size_t)BB * 32 * NN * 4);
    bf16*  Wg    = (bf16*) alloc((size_t)96 * KT * 2);
    bf16*  Wu    = (bf16*) alloc((size_t)32 * KT * 2);
    bf16*  Abf   = (bf16*) (ws + off);
    const bool useA = (off + (size_t)16 * NN * NN * 2) <= ws_size;

    prep_weights<<<156, 256, 0, stream>>>(gate_w, upd_w, Wg, Wu);
    if (useA) a2bf<<<2048, 256, 0, stream>>>(sup, Abf);
    prep_nodes<<<256, 256, 0, stream>>>(xt, s1, s2, ge, mlp_w, mlp_b, state, T);

    if (useA) {
        gemm_direct<0><<<dim3(32, 16), 256, 0, stream>>>(sup, Abf, T, 0, 0, 1, 3);
        gemm_direct<0><<<dim3(32, 16), 256, 0, stream>>>(sup, Abf, T, 1, 3, 2, 4);
        proj_gate<<<dim3(32, 8), 256, 0, stream>>>(T, Wg, gate_b, s1, s2, T, rT);
        gemm_direct<0><<<dim3(32, 16), 256, 0, stream>>>(sup, Abf, T, 0, 0, 1, 3);
        gemm_direct<0><<<dim3(32, 16), 256, 0, stream>>>(sup, Abf, T, 1, 3, 2, 4);
    } else {
        gemm_direct<1><<<dim3(32, 16), 256, 0, stream>>>(sup, Abf, T, 0, 0, 1, 3);
        gemm_direct<1><<<dim3(32, 16), 256, 0, stream>>>(sup, Abf, T, 1, 3, 2, 4);
        proj_gate<<<dim3(32, 8), 256, 0, stream>>>(T, Wg, gate_b, s1, s2, T, rT);
        gemm_direct<1><<<dim3(32, 16), 256, 0, stream>>>(sup, Abf, T, 0, 0, 1, 3);
        gemm_direct<1><<<dim3(32, 16), 256, 0, stream>>>(sup, Abf, T, 1, 3, 2, 4);
    }
    proj_upd<<<dim3(32, 8), 256, 0, stream>>>(T, Wu, upd_b, state, rT, hop_w, hop_b, out);
}

// Round 7
// 547.878 us; speedup vs baseline: 1.4271x; 1.4271x over previous
//
#include <hip/hip_runtime.h>

#define NN 2048
#define BB 8
#define KT 416            // 5 slots * 80 rows + 16 zero pad rows
#define SLOT (80 * NN)

typedef __bf16 bf16;
typedef __bf16 bf16x4 __attribute__((ext_vector_type(4)));
typedef __bf16 bf16x8 __attribute__((ext_vector_type(8)));
typedef float  f32x4  __attribute__((ext_vector_type(4)));

// Barrier that waits ONLY on LDS ops (lgkmcnt) — used by proj kernels.
__device__ __forceinline__ void bar_lgkm() {
    asm volatile("s_waitcnt lgkmcnt(0)" ::: "memory");
    __builtin_amdgcn_s_barrier();
}

// Async global->LDS 16B copy. LDS dest must be wave-uniform (HW adds lane*16).
__device__ __forceinline__ void gld16(const bf16* g, char* l) {
    __builtin_amdgcn_global_load_lds(
        (const __attribute__((address_space(1))) unsigned int*)g,
        (__attribute__((address_space(3))) unsigned int*)l, 16, 0, 0);
}

// ---------------------------------------------------------------------------
// K0: fold Chebyshev (T2 = 2A^2x - x) + duplicated-X blocks into transposed
// bf16 weights Wg'[96][416], Wu'[32][416]; k = t*80 + c, pad cols zeroed.
// ---------------------------------------------------------------------------
__global__ void prep_weights(const float* __restrict__ gw, const float* __restrict__ uw,
                             bf16* __restrict__ Wg, bf16* __restrict__ Wu)
{
    int i = blockIdx.x * 256 + threadIdx.x;
    if (i < 96 * KT) {
        int o = i / KT, k = i % KT, t = k / 80, c = k % 80;
        float v = 0.0f;
        if (c < 66) {
            if (t == 0)      v = gw[c*96+o] - gw[(132+c)*96+o] + gw[(198+c)*96+o] - gw[(330+c)*96+o];
            else if (t == 1) v = gw[(66+c)*96+o];
            else if (t == 2) v = 2.0f * gw[(132+c)*96+o];
            else if (t == 3) v = gw[(264+c)*96+o];
            else             v = 2.0f * gw[(330+c)*96+o];
        }
        Wg[i] = (bf16)v;
    }
    if (i < 32 * KT) {
        int o = i / KT, k = i % KT, t = k / 80, c = k % 80;
        float v = 0.0f;
        if (c < 66) {
            if (t == 0)      v = uw[c*32+o] - uw[(132+c)*32+o] + uw[(198+c)*32+o] - uw[(330+c)*32+o];
            else if (t == 1) v = uw[(66+c)*32+o];
            else if (t == 2) v = 2.0f * uw[(132+c)*32+o];
            else if (t == 3) v = uw[(264+c)*32+o];
            else             v = 2.0f * uw[(330+c)*32+o];
        }
        Wu[i] = (bf16)v;
    }
}

// ---------------------------------------------------------------------------
// K0b: streaming f32 -> bf16 convert of all 16 support matrices (268->134 MB),
// fully linear loads/stores at HBM speed. All 4 gemm hops then read bf16.
// ---------------------------------------------------------------------------
__global__ __launch_bounds__(256)
void a2bf(const float* __restrict__ s, bf16* __restrict__ d)
{
    const float4* s4 = (const float4*)s;
    uint4* d4 = (uint4*)d;
    const size_t n8 = (size_t)16 * NN * NN / 8;
    for (size_t i = (size_t)blockIdx.x * 256 + threadIdx.x; i < n8;
         i += (size_t)gridDim.x * 256) {
        float4 u = s4[2 * i], v = s4[2 * i + 1];
        bf16x8 r;
        r[0]=(bf16)u.x; r[1]=(bf16)u.y; r[2]=(bf16)u.z; r[3]=(bf16)u.w;
        r[4]=(bf16)v.x; r[5]=(bf16)v.y; r[6]=(bf16)v.z; r[7]=(bf16)v.w;
        d4[i] = *(uint4*)&r;
    }
}

// ---------------------------------------------------------------------------
// K1: 64-node tiles. mr = sigmoid(gate_in@mlp_w+b), state = mr*s1+(1-mr)*s2,
// build T slot0 = X^T basis (rows 0..79, pads zero) with coalesced 128B row
// writes via LDS transpose. Also zeroes T pad rows 400..415.
// ---------------------------------------------------------------------------
__global__ __launch_bounds__(256)
void prep_nodes(const float* __restrict__ xt, const float* __restrict__ s1,
                const float* __restrict__ s2, const float* __restrict__ ge,
                const float* __restrict__ mlp_w, const float* __restrict__ mlp_b,
                float* __restrict__ state, bf16* __restrict__ T)
{
    __shared__ float wl[74 * 32];
    __shared__ float bl[32];
    __shared__ __align__(16) float statel[64][36];
    __shared__ __align__(16) bf16  Xl[80][72];
    const int tid = threadIdx.x;

    for (int i = tid; i < 592; i += 256) ((float4*)wl)[i] = ((const float4*)mlp_w)[i];
    if (tid < 32) bl[tid] = mlp_b[tid];
    {   // zero T pad rows (rows 400..415 per batch): this block's 2KB chunk
        int bb = blockIdx.x >> 5, chunk = blockIdx.x & 31;
        uint2* dst = (uint2*)((char*)T + ((size_t)bb * KT * NN + 400 * NN) * 2 + (size_t)chunk * 2048);
        dst[tid] = make_uint2(0u, 0u);
    }
    for (int i = tid; i < 14 * 64; i += 256) Xl[66 + (i >> 6)][i & 63] = (bf16)0.0f;
    __syncthreads();

    const int nl = tid & 63, og = tid >> 6, o0 = og * 8;
    const size_t node0 = (size_t)blockIdx.x * 64;
    const size_t node = node0 + nl;
    const int b = (int)(node0 >> 11);
    const int nb0 = (int)(node0 & 2047);
    const float* p1 = s1 + node * 32;
    const float* p2 = s2 + node * 32;
    const float* pg = ge + node * 8;

    float acc[8];
    #pragma unroll
    for (int j = 0; j < 8; ++j) acc[j] = bl[o0 + j];
    float2 px = *(const float2*)(xt + node * 2);
    #pragma unroll
    for (int j = 0; j < 8; ++j) acc[j] += px.x * wl[o0 + j] + px.y * wl[32 + o0 + j];

    float k1[8], k2[8];
    #pragma unroll
    for (int ii = 0; ii < 8; ++ii) {
        float4 v = *(const float4*)(p1 + ii * 4);
        const float* vp = (const float*)&v;
        if (ii == 2 * og)     { k1[0]=vp[0]; k1[1]=vp[1]; k1[2]=vp[2]; k1[3]=vp[3]; }
        if (ii == 2 * og + 1) { k1[4]=vp[0]; k1[5]=vp[1]; k1[6]=vp[2]; k1[7]=vp[3]; }
        #pragma unroll
        for (int p = 0; p < 4; ++p) {
            #pragma unroll
            for (int j = 0; j < 8; ++j) acc[j] += vp[p] * wl[(2 + ii*4 + p) * 32 + o0 + j];
        }
    }
    #pragma unroll
    for (int ii = 0; ii < 8; ++ii) {
        float4 v = *(const float4*)(p2 + ii * 4);
        const float* vp = (const float*)&v;
        if (ii == 2 * og)     { k2[0]=vp[0]; k2[1]=vp[1]; k2[2]=vp[2]; k2[3]=vp[3]; }
        if (ii == 2 * og + 1) { k2[4]=vp[0]; k2[5]=vp[1]; k2[6]=vp[2]; k2[7]=vp[3]; }
        #pragma unroll
        for (int p = 0; p < 4; ++p) {
            #pragma unroll
            for (int j = 0; j < 8; ++j) acc[j] += vp[p] * wl[(34 + ii*4 + p) * 32 + o0 + j];
        }
    }
    #pragma unroll
    for (int ii = 0; ii < 2; ++ii) {
        float4 v = *(const float4*)(pg + ii * 4);
        const float* vp = (const float*)&v;
        #pragma unroll
        for (int p = 0; p < 4; ++p) {
            #pragma unroll
            for (int j = 0; j < 8; ++j) acc[j] += vp[p] * wl[(66 + ii*4 + p) * 32 + o0 + j];
        }
    }
    #pragma unroll
    for (int j = 0; j < 8; ++j) {
        float mr = 1.0f / (1.0f + __expf(-acc[j]));
        statel[nl][o0 + j] = mr * k1[j] + (1.0f - mr) * k2[j];
        Xl[2 + o0 + j][nl]  = (bf16)k1[j];
        Xl[34 + o0 + j][nl] = (bf16)k2[j];
    }
    if (og == 0) { Xl[0][nl] = (bf16)px.x; Xl[1][nl] = (bf16)px.y; }
    __syncthreads();

    for (int i = tid; i < 512; i += 256) {
        int n_ = i >> 3, c = (i & 7) * 4;
        *(float4*)&state[node0 * 32 + n_ * 32 + c] = *(const float4*)&statel[n_][c];
    }
    bf16* Tb = T + (size_t)b * KT * NN;
    for (int i = tid; i < 640; i += 256) {
        int r = i >> 3, seg = i & 7;
        *(uint4*)(Tb + (size_t)r * NN + nb0 + seg * 8) = *(const uint4*)&Xl[r][seg * 8];
    }
}

// ---------------------------------------------------------------------------
// K2: C^T(80x2048 bf16) = A(2048x2048 bf16) @ T-slot.  m97-style async GEMM:
//  - A[64][64] + B[80][64] bf16 tiles per K-step, staged DIRECT global->LDS
//    via global_load_lds width-16 (no VGPR round trip); every global request
//    is a full 128B line (8 lanes x 16B contiguous per row) -> kills the
//    1.72x FETCH amplification measured in R5.
//  - 3 LDS buffers (55KB), prefetch depth 2; counted s_waitcnt vmcnt(N)
//    (never 0 in the loop, T4) + raw s_barrier; sched_barrier(0) fence.
//  - LDS XOR swizzle (kseg ^= row&7) applied on the SOURCE address (m173),
//    matching XOR on ds_read -> 16-way bank conflict down to ~2-way.
// ---------------------------------------------------------------------------
__global__ __launch_bounds__(256, 2)
void gemm_async(const bf16* __restrict__ Abf, bf16* __restrict__ T,
                int in0, int in1, int out0, int out1)
{
    __shared__ __align__(16) char smem[3 * 18432];   // per buf: A 8KB, B 10KB

    const int sb = blockIdx.y;
    const int s = sb >> 3, b = sb & 7;
    const int m0 = blockIdx.x * 64;
    const int tid = threadIdx.x, wave = tid >> 6, lane = tid & 63;
    const int frow = lane & 15;

    bf16* Tb = T + (size_t)b * KT * NN;
    const bf16* Bt = Tb + (size_t)(s ? in1 : in0) * SLOT;
    bf16*       Ct = Tb + (size_t)(s ? out1 : out0) * SLOT + m0;
    const bf16* Ap = Abf + (size_t)sb * NN * NN + (size_t)m0 * NN;

    const int t8  = lane >> 3;                 // row-within-8 from lane
    const int ksw = ((lane & 7) ^ t8) * 8;     // XOR-swizzled k-chunk (elems)

    // stage k-tile kt into buffer buf. Waves 0..3 cover A rows 0..63 and
    // B rows 0..63 (2 issues each); waves 0,1 add B rows 64..79.
    auto stage = [&](int buf, int kt) {
        const int k0 = kt * 64;
        char* lb = smem + buf * 18432;
        #pragma unroll
        for (int j = 0; j < 2; ++j) {
            const int row = j * 32 + wave * 8 + t8;
            gld16(Ap + (size_t)row * NN + k0 + ksw, lb + j * 4096 + wave * 1024);
            gld16(Bt + (size_t)row * NN + k0 + ksw, lb + 8192 + j * 4096 + wave * 1024);
        }
        if (wave < 2) {
            const int row = 64 + wave * 8 + t8;
            gld16(Bt + (size_t)row * NN + k0 + ksw, lb + 16384 + wave * 1024);
        }
    };

    f32x4 acc[5] = {};
    // swizzled fragment read: 16B at (row, kh*32 + (lane>>4)*8) of a [*][64] tile
    auto rd = [&](const char* base, int row, int kh) -> bf16x8 {
        int byte = (row * 128 + kh * 64 + ((lane >> 4) * 16)) ^ ((row & 7) << 4);
        return *(const bf16x8*)(base + byte);
    };
    auto compute = [&](int buf) {
        const char* lb = smem + buf * 18432;
        #pragma unroll
        for (int kh = 0; kh < 2; ++kh) {
            bf16x8 af = rd(lb, wave * 16 + frow, kh);
            #pragma unroll
            for (int ct = 0; ct < 5; ++ct) {
                bf16x8 bv = rd(lb + 8192, ct * 16 + frow, kh);
                acc[ct] = __builtin_amdgcn_mfma_f32_16x16x32_bf16(af, bv, acc[ct], 0, 0, 0);
            }
        }
    };

#define VMW(N01, N23) \
    if (wave < 2) { asm volatile("s_waitcnt vmcnt(" #N01 ")" ::: "memory"); } \
    else          { asm volatile("s_waitcnt vmcnt(" #N23 ")" ::: "memory"); } \
    __builtin_amdgcn_s_barrier(); \
    __builtin_amdgcn_sched_barrier(0);

#define GSTEP(BUF, STGBUF, KT_) \
    stage(STGBUF, (KT_) + 2); \
    VMW(10, 8) \
    compute(BUF); \
    __builtin_amdgcn_s_barrier();

    stage(0, 0);
    stage(1, 1);
    for (int it = 0; it < 30; it += 3) {
        GSTEP(0, 2, it)
        GSTEP(1, 0, it + 1)
        GSTEP(2, 1, it + 2)
    }
    // kt = 30: only tile 31 (5/4 issues) still in flight
    VMW(5, 4)
    compute(0);
    __builtin_amdgcn_s_barrier();
    // kt = 31: drain
    VMW(0, 0)
    compute(1);
#undef GSTEP
#undef VMW

    const int ccol = lane & 15;
    const int crow = (lane >> 4) * 4;
    #pragma unroll
    for (int ct = 0; ct < 5; ++ct) {
        bf16x4 o;
        o[0]=(bf16)acc[ct][0]; o[1]=(bf16)acc[ct][1]; o[2]=(bf16)acc[ct][2]; o[3]=(bf16)acc[ct][3];
        *(bf16x4*)&Ct[(size_t)(ct * 16 + ccol) * NN + wave * 16 + crow] = o;
    }
}

// ---------------------------------------------------------------------------
// Fallback gemm (no workspace for Abf): f32 A direct global->reg->MFMA.
// ---------------------------------------------------------------------------
__global__ __launch_bounds__(256, 2)
void gemm_f32(const float* __restrict__ Aall, bf16* __restrict__ T,
              int in0, int in1, int out0, int out1)
{
    const int sb = blockIdx.y;
    const int s = sb >> 3, b = sb & 7;
    const int m0 = blockIdx.x * 64;
    const int tid = threadIdx.x, wave = tid >> 6, lane = tid & 63;
    const int frow = lane & 15, fko = (lane >> 4) * 8;
    const int am = m0 + wave * 16 + frow;

    bf16* Tb = T + (size_t)b * KT * NN;
    const bf16* Bt = Tb + (size_t)(s ? in1 : in0) * SLOT;
    bf16*       Ct = Tb + (size_t)(s ? out1 : out0) * SLOT + m0;
    const float* Af = Aall + (size_t)sb * NN * NN + (size_t)am * NN + fko;
    const bf16*  Bp = Bt + (size_t)frow * NN + fko;

    f32x4 acc[5] = {};
    float4 gA[4], gB[4];
    uint4 bbA[5][2], bbB[5][2];

    auto ld = [&](float4 (&g)[4], uint4 (&bb)[5][2], int k0) {
        g[0] = *(const float4*)(Af + k0);
        g[1] = *(const float4*)(Af + k0 + 4);
        g[2] = *(const float4*)(Af + k0 + 32);
        g[3] = *(const float4*)(Af + k0 + 36);
        #pragma unroll
        for (int ct = 0; ct < 5; ++ct) {
            bb[ct][0] = *(const uint4*)(Bp + (size_t)ct * 16 * NN + k0);
            bb[ct][1] = *(const uint4*)(Bp + (size_t)ct * 16 * NN + k0 + 32);
        }
    };
    auto cv = [&](float4 g0, float4 g1) -> bf16x8 {
        bf16x8 r;
        r[0]=(bf16)g0.x; r[1]=(bf16)g0.y; r[2]=(bf16)g0.z; r[3]=(bf16)g0.w;
        r[4]=(bf16)g1.x; r[5]=(bf16)g1.y; r[6]=(bf16)g1.z; r[7]=(bf16)g1.w;
        return r;
    };
    auto comp = [&](float4 (&g)[4], uint4 (&bb)[5][2]) {
        bf16x8 af0 = cv(g[0], g[1]), af1 = cv(g[2], g[3]);
        #pragma unroll
        for (int ct = 0; ct < 5; ++ct)
            acc[ct] = __builtin_amdgcn_mfma_f32_16x16x32_bf16(af0, *(bf16x8*)&bb[ct][0], acc[ct], 0, 0, 0);
        #pragma unroll
        for (int ct = 0; ct < 5; ++ct)
            acc[ct] = __builtin_amdgcn_mfma_f32_16x16x32_bf16(af1, *(bf16x8*)&bb[ct][1], acc[ct], 0, 0, 0);
    };

    ld(gA, bbA, 0);
    ld(gB, bbB, 64);
    for (int it = 0; it < 32; it += 2) {
        comp(gA, bbA);
        if (it < 30) ld(gA, bbA, (it + 2) * 64);
        comp(gB, bbB);
        if (it < 29) ld(gB, bbB, (it + 3) * 64);
    }

    const int ccol = lane & 15;
    const int crow = (lane >> 4) * 4;
    #pragma unroll
    for (int ct = 0; ct < 5; ++ct) {
        bf16x4 o;
        o[0]=(bf16)acc[ct][0]; o[1]=(bf16)acc[ct][1]; o[2]=(bf16)acc[ct][2]; o[3]=(bf16)acc[ct][3];
        *(bf16x4*)&Ct[(size_t)(ct * 16 + ccol) * NN + wave * 16 + crow] = o;
    }
}

// ---------------------------------------------------------------------------
// K3: gate projection as MFMA GEMM: D[96][2048/b] = Wg'[96][416] @ T[416][2048].
// ---------------------------------------------------------------------------
__global__ __launch_bounds__(256)
void proj_gate(const bf16* T, const bf16* __restrict__ Wg, const float* __restrict__ gate_b,
               const float* __restrict__ s1, const float* __restrict__ s2,
               bf16* Tmut, float* __restrict__ rT)
{
    __shared__ __align__(16) bf16 Wl[96][424];
    __shared__ __align__(16) bf16 Bl[2][64][44];
    const int b = blockIdx.y, n0 = blockIdx.x * 64, tid = threadIdx.x;
    const bf16* Tb = T + (size_t)b * KT * NN;

    for (int i = tid; i < 96 * 52; i += 256) {
        int r = i / 52, seg = i % 52;
        *(uint4*)&Wl[r][seg * 8] = *(const uint4*)(Wg + (size_t)r * KT + seg * 8);
    }
    const int kk = tid >> 3, seg = tid & 7;
    uint4 rbA, rbB;
    auto gloadv = [&](uint4& r, int k0) { r = *(const uint4*)(Tb + (size_t)(k0 + kk) * NN + n0 + seg * 8); };
    auto scat = [&](int buf, uint4& r) {
        bf16 tmp[8]; *(uint4*)tmp = r;
        #pragma unroll
        for (int j = 0; j < 8; ++j) Bl[buf][seg * 8 + j][kk] = tmp[j];
    };
    const int lane = tid & 63, wave = tid >> 6;
    const int fr = lane & 15, qd = lane >> 4;

    f32x4 acc[6] = {};
    auto comp = [&](int buf, int st) {
        bf16x8 bv = *(const bf16x8*)&Bl[buf][wave * 16 + fr][qd * 8];
        #pragma unroll
        for (int f = 0; f < 6; ++f) {
            bf16x8 av = *(const bf16x8*)&Wl[f * 16 + fr][st * 32 + qd * 8];
            acc[f] = __builtin_amdgcn_mfma_f32_16x16x32_bf16(av, bv, acc[f], 0, 0, 0);
        }
    };

    gloadv(rbA, 0); gloadv(rbB, 32);
    for (int st = 0; st < 12; st += 2) {
        scat(0, rbA);
        gloadv(rbA, (st + 2) * 32);
        bar_lgkm();
        comp(0, st);
        scat(1, rbB);
        if (st < 10) gloadv(rbB, (st + 3) * 32);
        bar_lgkm();
        comp(1, st + 1);
    }
    scat(0, rbA);
    bar_lgkm();
    comp(0, 12);

    const int nn = n0 + wave * 16 + fr;
    const size_t node = (size_t)b * NN + nn;
    bf16* Cd = Tmut + (size_t)b * KT * NN;   // slot 0
    #pragma unroll
    for (int f = 0; f < 6; ++f) {
        const int o0 = f * 16 + qd * 4;
        float4 gb4 = *(const float4*)(gate_b + o0);
        const float* gb = (const float*)&gb4;
        float sg[4];
        #pragma unroll
        for (int r = 0; r < 4; ++r) sg[r] = 1.0f / (1.0f + __expf(-(acc[f][r] + gb[r])));
        if (f < 2) {
            float4 sv4 = *(const float4*)(s1 + node * 32 + o0);
            const float* sv = (const float*)&sv4;
            #pragma unroll
            for (int r = 0; r < 4; ++r) Cd[(size_t)(2 + o0 + r) * NN + nn] = (bf16)(sg[r] * sv[r]);
        } else if (f < 4) {
            const int oo = o0 - 32;
            float4 sv4 = *(const float4*)(s2 + node * 32 + oo);
            const float* sv = (const float*)&sv4;
            #pragma unroll
            for (int r = 0; r < 4; ++r) Cd[(size_t)(34 + oo + r) * NN + nn] = (bf16)(sg[r] * sv[r]);
        } else {
            const int oo = o0 - 64;
            #pragma unroll
            for (int r = 0; r < 4; ++r) rT[((size_t)b * 32 + oo + r) * NN + nn] = sg[r];
        }
    }
}

// ---------------------------------------------------------------------------
// K4: update projection: D[32][2048/b] = Wu'[32][416] @ T[416][2048];
// hc = tanh, h = r*state+(1-r)*hc, transnext = h@hop_w+b.
// ---------------------------------------------------------------------------
__global__ __launch_bounds__(256)
void proj_upd(const bf16* __restrict__ T, const bf16* __restrict__ Wu,
              const float* __restrict__ upd_b, const float* __restrict__ state,
              const float* __restrict__ rT, const float* __restrict__ hop_w,
              const float* __restrict__ hop_b, float* __restrict__ out)
{
    __shared__ __align__(16) bf16 Wl[32][424];
    __shared__ __align__(16) bf16 Bl[2][64][44];
    __shared__ __align__(16) float hsh[64][36];
    __shared__ float hw[1024];
    const int b = blockIdx.y, n0 = blockIdx.x * 64, tid = threadIdx.x;
    const bf16* Tb = T + (size_t)b * KT * NN;

    for (int i = tid; i < 32 * 52; i += 256) {
        int r = i / 52, seg = i % 52;
        *(uint4*)&Wl[r][seg * 8] = *(const uint4*)(Wu + (size_t)r * KT + seg * 8);
    }
    for (int i = tid; i < 256; i += 256) ((float4*)hw)[i] = ((const float4*)hop_w)[i];
    const int kk = tid >> 3, seg = tid & 7;
    uint4 rbA, rbB;
    auto gloadv = [&](uint4& r, int k0) { r = *(const uint4*)(Tb + (size_t)(k0 + kk) * NN + n0 + seg * 8); };
    auto scat = [&](int buf, uint4& r) {
        bf16 tmp[8]; *(uint4*)tmp = r;
        #pragma unroll
        for (int j = 0; j < 8; ++j) Bl[buf][seg * 8 + j][kk] = tmp[j];
    };
    const int lane = tid & 63, wave = tid >> 6;
    const int fr = lane & 15, qd = lane >> 4;

    f32x4 acc[2] = {};
    auto comp = [&](int buf, int st) {
        bf16x8 bv = *(const bf16x8*)&Bl[buf][wave * 16 + fr][qd * 8];
        #pragma unroll
        for (int f = 0; f < 2; ++f) {
            bf16x8 av = *(const bf16x8*)&Wl[f * 16 + fr][st * 32 + qd * 8];
            acc[f] = __builtin_amdgcn_mfma_f32_16x16x32_bf16(av, bv, acc[f], 0, 0, 0);
        }
    };

    gloadv(rbA, 0); gloadv(rbB, 32);
    for (int st = 0; st < 12; st += 2) {
        scat(0, rbA);
        gloadv(rbA, (st + 2) * 32);
        bar_lgkm();
        comp(0, st);
        scat(1, rbB);
        if (st < 10) gloadv(rbB, (st + 3) * 32);
        bar_lgkm();
        comp(1, st + 1);
    }
    scat(0, rbA);
    bar_lgkm();
    comp(0, 12);

    const int nn = n0 + wave * 16 + fr;
    const size_t node = (size_t)b * NN + nn;
    const int nl = wave * 16 + fr;
    #pragma unroll
    for (int f = 0; f < 2; ++f) {
        const int o0 = f * 16 + qd * 4;
        float4 ub4 = *(const float4*)(upd_b + o0);
        const float* ub = (const float*)&ub4;
        float4 st4 = *(const float4*)(state + node * 32 + o0);
        const float* sv = (const float*)&st4;
        #pragma unroll
        for (int r = 0; r < 4; ++r) {
            const int o = o0 + r;
            float hc = tanhf(acc[f][r] + ub[r]);
            float rv = rT[((size_t)b * 32 + o) * NN + nn];
            hsh[nl][o] = rv * sv[r] + (1.0f - rv) * hc;
        }
    }
    __syncthreads();

    const int nl2 = tid & 63, og = tid >> 6;
    const size_t node2 = (size_t)b * NN + n0 + nl2;
    float tac[8];
    #pragma unroll
    for (int j = 0; j < 8; ++j) tac[j] = hop_b[og * 8 + j];
    #pragma unroll
    for (int kc = 0; kc < 8; ++kc) {
        float4 hv4 = *(const float4*)&hsh[nl2][kc * 4];
        const float* hv = (const float*)&hv4;
        #pragma unroll
        for (int p = 0; p < 4; ++p) {
            #pragma unroll
            for (int j = 0; j < 8; ++j) tac[j] += hv[p] * hw[(kc * 4 + p) * 32 + og * 8 + j];
        }
    }
    float* out2 = out + (size_t)BB * NN * 32;
    *(float4*)&out[node2 * 32 + og * 8]     = *(const float4*)&hsh[nl2][og * 8];
    *(float4*)&out[node2 * 32 + og * 8 + 4] = *(const float4*)&hsh[nl2][og * 8 + 4];
    float4 t0; float* t0p = (float*)&t0;
    t0p[0]=tac[0]; t0p[1]=tac[1]; t0p[2]=tac[2]; t0p[3]=tac[3];
    *(float4*)&out2[node2 * 32 + og * 8] = t0;
    t0p[0]=tac[4]; t0p[1]=tac[5]; t0p[2]=tac[6]; t0p[3]=tac[7];
    *(float4*)&out2[node2 * 32 + og * 8 + 4] = t0;
}

// ---------------------------------------------------------------------------
extern "C" void kernel_launch(void* const* d_in, const int* in_sizes, int n_in,
                              void* d_out, int out_size, void* d_ws, size_t ws_size,
                              hipStream_t stream)
{
    const float* xt     = (const float*)d_in[0];
    const float* s1     = (const float*)d_in[1];
    const float* s2     = (const float*)d_in[2];
    const float* ge     = (const float*)d_in[3];
    const float* sup    = (const float*)d_in[4];
    const float* mlp_w  = (const float*)d_in[5];
    const float* mlp_b  = (const float*)d_in[6];
    const float* gate_w = (const float*)d_in[7];
    const float* gate_b = (const float*)d_in[8];
    const float* upd_w  = (const float*)d_in[9];
    const float* upd_b  = (const float*)d_in[10];
    const float* hop_w  = (const float*)d_in[11];
    const float* hop_b  = (const float*)d_in[12];
    float* out = (float*)d_out;

    char* ws = (char*)d_ws;
    size_t off = 0;
    auto alloc = [&](size_t bytes) -> void* {
        void* p = ws + off;
        off += (bytes + 255) & ~(size_t)255;
        return p;
    };
    bf16*  T     = (bf16*) alloc((size_t)BB * KT * NN * 2);
    float* state = (float*)alloc((size_t)BB * NN * 32 * 4);
    float* rT    = (float*)alloc((size_t)BB * 32 * NN * 4);
    bf16*  Wg    = (bf16*) alloc((size_t)96 * KT * 2);
    bf16*  Wu    = (bf16*) alloc((size_t)32 * KT * 2);
    bf16*  Abf   = (bf16*) (ws + off);
    const bool useA = (off + (size_t)16 * NN * NN * 2) <= ws_size;

    prep_weights<<<156, 256, 0, stream>>>(gate_w, upd_w, Wg, Wu);
    if (useA) a2bf<<<2048, 256, 0, stream>>>(sup, Abf);
    prep_nodes<<<256, 256, 0, stream>>>(xt, s1, s2, ge, mlp_w, mlp_b, state, T);

    if (useA) {
        gemm_async<<<dim3(32, 16), 256, 0, stream>>>(Abf, T, 0, 0, 1, 3);
        gemm_async<<<dim3(32, 16), 256, 0, stream>>>(Abf, T, 1, 3, 2, 4);
        proj_gate<<<dim3(32, 8), 256, 0, stream>>>(T, Wg, gate_b, s1, s2, T, rT);
        gemm_async<<<dim3(32, 16), 256, 0, stream>>>(Abf, T, 0, 0, 1, 3);
        gemm_async<<<dim3(32, 16), 256, 0, stream>>>(Abf, T, 1, 3, 2, 4);
    } else {
        gemm_f32<<<dim3(32, 16), 256, 0, stream>>>(sup, T, 0, 0, 1, 3);
        gemm_f32<<<dim3(32, 16), 256, 0, stream>>>(sup, T, 1, 3, 2, 4);
        proj_gate<<<dim3(32, 8), 256, 0, stream>>>(T, Wg, gate_b, s1, s2, T, rT);
        gemm_f32<<<dim3(32, 16), 256, 0, stream>>>(sup, T, 0, 0, 1, 3);
        gemm_f32<<<dim3(32, 16), 256, 0, stream>>>(sup, T, 1, 3, 2, 4);
    }
    proj_upd<<<dim3(32, 8), 256, 0, stream>>>(T, Wu, upd_b, state, rT, hop_w, hop_b, out);
}